// Round 19
// baseline (542.214 us; speedup 1.0000x reference)
//
#include <hip/hip_runtime.h>
#include <hip/hip_bf16.h>
#include <math.h>

// ---------------------------------------------------------------------------
// RealSymplecticReactionDiffusion2D — round 18
//  B=8, N=4096 (64x64), d=768, k_steps=4 (read from device)
// Stages:
//  1) transpose_x (FUSED pool partials) -> xT + partial
//  2) pool_reduce -> pooled[8][768]
//  3) gamma_kernel -> gamma[8][768]
//  4) cvt_bf16 (W_out -> bf16)
//  5) pde_kernel: R7-verified wave-per-channel math; ONLY the final write
//     changed: 128 global_store_short directly into A_blk[b][g][n][4ch]
//     (4 waves of a block fill the 4 interleaved 2B slots of each 8B chunk;
//     L2 merges partial lines).  transpose_uv ELIMINATED (-35us, -200MB).
//  6) gemm_kernel: R7 skeleton (2-buf BK=64, vmcnt(8), XCD remap, B-swizzle);
//     A staged from A_blk: [16g][128n][4ch] LDS tile, frag = 2x ds_read_b64
//     at g*512+row*4 (bank-minimal, conflict-free).
//  Workspace: A_blk@0 (partial aliases it, dead before pde); xT@96MB (no
//  alias with A_blk — pde reads xT while writing A_blk).
// ---------------------------------------------------------------------------

typedef __attribute__((ext_vector_type(8))) short short8v;
typedef __attribute__((ext_vector_type(4))) short short4v;
typedef __attribute__((ext_vector_type(4))) float float4v;

static __device__ __forceinline__ unsigned short f2bf(float f) {
  unsigned u = __builtin_bit_cast(unsigned, f);
  u += 0x7FFFu + ((u >> 16) & 1u);   // round-to-nearest-even
  return (unsigned short)(u >> 16);
}

static __device__ __forceinline__ float softplusf(float x) {
  return (x > 20.0f) ? x : log1pf(expf(x));
}

// ---------------- transpose x [B,N,768] -> xT [B,768,N]  (+ pool partials) --
__global__ __launch_bounds__(256) void transpose_x_kernel(const float* __restrict__ x,
                                                          float* __restrict__ xT,
                                                          float* __restrict__ partial) {
  __shared__ float tile[64][65];
  __shared__ float red[4][64];
  const int c0 = blockIdx.x * 64;   // 12 tiles
  const int n0 = blockIdx.y * 64;   // 64 tiles
  const int b  = blockIdx.z;        // 8
  const int tl = threadIdx.x & 63;
  const int tw = threadIdx.x >> 6;  // 0..3
  const float* src = x + ((size_t)b * 4096 + n0) * 768 + c0;
  float s = 0.0f;
  #pragma unroll
  for (int j = 0; j < 16; ++j) {
    const int n = j * 4 + tw;
    const float val = src[(size_t)n * 768 + tl];
    tile[n][tl] = val;
    s += val;
  }
  red[tw][tl] = s;
  __syncthreads();
  if (tw == 0) {
    partial[((size_t)blockIdx.y * 8 + b) * 768 + c0 + tl] =
        red[0][tl] + red[1][tl] + red[2][tl] + red[3][tl];
  }
  float* dst = xT + ((size_t)b * 768 + c0) * 4096 + n0;
  #pragma unroll
  for (int j = 0; j < 16; ++j) {
    const int cc = j * 4 + tw;
    dst[(size_t)cc * 4096 + tl] = tile[tl][cc];
  }
}

__global__ void pool_reduce_kernel(const float* __restrict__ partial, float* __restrict__ pooled) {
  const int idx = blockIdx.x * 256 + threadIdx.x;   // 0..6143 = b*768+c
  float s = 0.0f;
  #pragma unroll
  for (int j = 0; j < 64; ++j) s += partial[(size_t)j * 6144 + idx];
  pooled[idx] = s * (1.0f / 4096.0f);
}

// ---------------- diffusion gate ----------------
__global__ void gamma_kernel(const float* __restrict__ pooled, const float* __restrict__ Wg,
                             const float* __restrict__ bg, float* __restrict__ gamma) {
  const int lane = threadIdx.x & 63;
  const int w = threadIdx.x >> 6;
  const int o = blockIdx.x * 4 + w;
  const int b = o / 768;
  const int j = o - b * 768;
  const float* pr = pooled + b * 768;
  const float* wr = Wg + (size_t)j * 768;
  float s = 0.0f;
  #pragma unroll
  for (int c = lane; c < 768; c += 64) s += pr[c] * wr[c];
  #pragma unroll
  for (int off = 32; off > 0; off >>= 1) s += __shfl_down(s, off);
  if (lane == 0) {
    float gin = s + bg[j];
    gamma[o] = fminf(softplusf(gin), 0.05f);
  }
}

// ---------------- W_out -> bf16 ----------------
__global__ void cvt_bf16_kernel(const float* __restrict__ src, unsigned short* __restrict__ dst, int n) {
  int i = blockIdx.x * 256 + threadIdx.x;
  if (i < n) dst[i] = f2bf(src[i]);
}

// ---------------- symplectic reaction-diffusion PDE (wave-per-channel) ------
// R7-verified math/load; final write replaced: scalar bf16 stores into
// A_blk[b][g][n][4ch] (elem off ((b*384+g)*4096+n)*4+ch). Block = channels
// c0..c0+3 (c0 4-aligned); wave w = ch slot w. u -> g=c0>>2, v -> 192+(c0>>2).
__global__ __launch_bounds__(256, 1) void pde_kernel(
    const float* __restrict__ xT, const float* __restrict__ gamma,
    const float* __restrict__ alpha, const float* __restrict__ beta,
    const int* __restrict__ kp, unsigned short* __restrict__ Ablk) {
  const int w = threadIdx.x >> 6;          // wave 0..3 (independent channels)
  const int lane = threadIdx.x & 63;
  const int b = blockIdx.x / 192;          // 1536 blocks = 8 b x 192 cgroups
  const int cg = blockIdx.x - b * 192;
  const int c = cg * 4 + w;
  const int lx = lane & 7;
  const int ly = lane >> 3;

  int ks = *kp; if (ks < 1) ks = 1;
  const float dt = 1.0f / (float)ks;
  const float hdt = 0.5f * dt;
  const float ae = 0.2f * tanhf(alpha[c]);
  const float be = fmaxf(softplusf(beta[c]), 1e-4f);
  const float g = gamma[b * 768 + c];
  const float c1n = -0.5f * dt * g;   // v -= c1*lap  ->  v += c1n*lap
  const float c2p = dt * g;

  const int laneL = (ly << 3) | ((lx + 7) & 7);
  const int laneR = (ly << 3) | ((lx + 1) & 7);
  const int laneU = (((ly + 7) & 7) << 3) | lx;   // holds rows above (row-1)
  const int laneD = (((ly + 1) & 7) << 3) | lx;   // holds rows below (row+1)

  float u[64], v[64];
  const float* xp = xT + ((size_t)b * 768 + c) * 4096;
  #pragma unroll
  for (int r = 0; r < 8; ++r) {
    const float4* src = (const float4*)(xp + (ly * 8 + r) * 64 + lx * 8);
    const float4 a0 = src[0], a1 = src[1];
    u[r * 8 + 0] = a0.x; u[r * 8 + 1] = a0.y; u[r * 8 + 2] = a0.z; u[r * 8 + 3] = a0.w;
    u[r * 8 + 4] = a1.x; u[r * 8 + 5] = a1.y; u[r * 8 + 6] = a1.z; u[r * 8 + 7] = a1.w;
  }
  #pragma unroll
  for (int i = 0; i < 64; ++i) v[i] = 0.0f;

  // G += COEF * lap(F): halo via 32 shfls, interior in-register.
  #define LAP_PHASE(F, G, COEF)                                               \
    {                                                                         \
      float lh[8], rh[8], uh[8], dh[8];                                       \
      _Pragma("unroll")                                                       \
      for (int r = 0; r < 8; ++r) {                                           \
        lh[r] = __shfl(F[r * 8 + 7], laneL);                                  \
        rh[r] = __shfl(F[r * 8 + 0], laneR);                                  \
        uh[r] = __shfl(F[56 + r], laneU);                                     \
        dh[r] = __shfl(F[r], laneD);                                          \
      }                                                                       \
      _Pragma("unroll")                                                       \
      for (int r = 0; r < 8; ++r) {                                           \
        _Pragma("unroll")                                                     \
        for (int j = 0; j < 8; ++j) {                                         \
          const float lf = (j == 0) ? lh[r] : F[r * 8 + j - 1];               \
          const float rt = (j == 7) ? rh[r] : F[r * 8 + j + 1];               \
          const float up = (r == 0) ? uh[j] : F[(r - 1) * 8 + j];             \
          const float dn = (r == 7) ? dh[j] : F[(r + 1) * 8 + j];             \
          const float lap = (lf + rt) + (up + dn) - 4.0f * F[r * 8 + j];      \
          G[r * 8 + j] = fmaf((COEF), lap, G[r * 8 + j]);                     \
        }                                                                     \
      }                                                                       \
    }

  for (int s = 0; s < ks; ++s) {
    #pragma unroll
    for (int i = 0; i < 64; ++i) {
      const float q = u[i] * u[i] + v[i] * v[i];
      const float rate = fminf(fmaxf(ae - be * q, -1.0f), 1.0f);
      const float t = hdt * rate;
      u[i] = fmaf(t, u[i], u[i]);
      v[i] = fmaf(t, v[i], v[i]);
    }
    LAP_PHASE(u, v, c1n)
    LAP_PHASE(v, u, c2p)
    LAP_PHASE(u, v, c1n)
    #pragma unroll
    for (int i = 0; i < 64; ++i) {
      const float q = u[i] * u[i] + v[i] * v[i];
      const float rate = fminf(fmaxf(ae - be * q, -1.0f), 1.0f);
      const float t = hdt * rate;
      u[i] = fmaf(t, u[i], u[i]);
      v[i] = fmaf(t, v[i], v[i]);
    }
  }
  #undef LAP_PHASE

  // write A_blk directly: u -> group cg, v -> group 192+cg; ch slot = w.
  // Scalar 2B stores; the block's 4 waves interleave-fill each 8B chunk and
  // L2 merges partial lines (block-local in time).
  unsigned short* au = Ablk + ((size_t)(b * 384 + cg) * 4096) * 4 + w;
  unsigned short* av = Ablk + ((size_t)(b * 384 + 192 + cg) * 4096) * 4 + w;
  #pragma unroll
  for (int r = 0; r < 8; ++r) {
    const int n = (ly * 8 + r) * 64 + lx * 8;
    #pragma unroll
    for (int j = 0; j < 8; ++j) {
      au[(size_t)(n + j) * 4] = f2bf(u[r * 8 + j]);
      av[(size_t)(n + j) * 4] = f2bf(v[r * 8 + j]);
    }
  }
}

// ---------------- bf16 MFMA GEMM (R7 skeleton, A from A_blk) ----------------
// out = A @ W^T + x*D.  128x128 tile, BK=64 (=16 groups of 4ch), 2-buf LDS,
// vmcnt(8), XCD remap.  A LDS tile [16g][128n][4ch] (512 hw per g), staged
// 1KB-contiguous; frag = 2x ds_read_b64 at g*512+row*4 (conflict-free:
// 4 quarter-waves x 128B contiguous = 4 bank-cycles, the minimum).
// B path/swizzle/epilogue R7-exact.
__global__ __launch_bounds__(256) void gemm_kernel(
    const unsigned short* __restrict__ Ablk, // [8][384][4096][4] bf16
    const unsigned short* __restrict__ Bt,   // [768][1536] bf16 (W_out)
    const float* __restrict__ x,             // [32768][768]
    const float* __restrict__ Dv,            // [768]
    float* __restrict__ out) {               // [32768][768]
  __shared__ __align__(16) unsigned short Als[2][128 * 64];
  __shared__ __align__(16) unsigned short Bls[2][128 * 64];
  const int tid = threadIdx.x;
  const int lane = tid & 63;
  const int w = tid >> 6;       // wave 0..3
  const int wr = w >> 1;        // wave row (2x2 waves, each 64x64 of C)
  const int wc = w & 1;

  // XCD-chunked remap: id -> (m-block, n-block). 1536 blocks, 8 XCDs.
  const int id = blockIdx.x;
  const int xcd = id & 7;
  const int seq = id >> 3;          // 0..191
  const int nb = seq % 6;
  const int mb = (seq / 6) * 8 + xcd;
  const int m0 = mb * 128;
  const int n0 = nb * 128;
  const int bb = m0 >> 12;          // batch of this m-panel
  const int nb0 = m0 & 4095;        // n offset within batch

  // B staging swizzle (R7): load global logical slot (lane&7)^(lane>>3)
  const int src_col = (((lane & 7) ^ (lane >> 3)) * 8);   // halfwords
  // read-side (B): quarter-wave q, row-low bits rlow
  const int q = lane >> 4;
  const int rlow = lane & 7;

  float4v acc[4][4];
  #pragma unroll
  for (int a = 0; a < 4; ++a)
    #pragma unroll
    for (int bq = 0; bq < 4; ++bq)
      acc[a][bq] = (float4v){0.f, 0.f, 0.f, 0.f};

  // per-wave: 4 A + 4 B global_load_lds, 16B each (vmcnt budget 8, as R7)
  #define STAGE(bufi, kt)                                                     \
    _Pragma("unroll")                                                         \
    for (int i = 0; i < 4; ++i) {                                             \
      const int g_off = w * 4 + i;          /* 0..15 */                       \
      __builtin_amdgcn_global_load_lds(                                       \
          (const __attribute__((address_space(1))) void*)(Ablk + ((size_t)(bb * 384 + (kt) * 16 + g_off) * 4096 + nb0) * 4 + lane * 8), \
          (__attribute__((address_space(3))) void*)(&Als[bufi][g_off * 512]), 16, 0, 0); \
      const int rowblk = g_off * 8;                                           \
      const int row = rowblk + (lane >> 3);                                   \
      __builtin_amdgcn_global_load_lds(                                       \
          (const __attribute__((address_space(1))) void*)(Bt + (size_t)(n0 + row) * 1536 + (kt) * 64 + src_col), \
          (__attribute__((address_space(3))) void*)(&Bls[bufi][rowblk * 64]), 16, 0, 0); \
    }

  STAGE(0, 0)
  int cur = 0;
  for (int kt = 0; kt < 24; ++kt) {
    // bar1: all waves' reads of buf[cur^1] retired -> safe to re-stage
    __builtin_amdgcn_s_barrier();
    if (kt < 23) {
      STAGE(cur ^ 1, kt + 1)
      asm volatile("s_waitcnt vmcnt(8)" ::: "memory");   // wait prev 8, keep new 8 in flight
    } else {
      asm volatile("s_waitcnt vmcnt(0)" ::: "memory");   // last tile: drain
    }
    // bar2: every wave has its current buffer's loads complete
    __builtin_amdgcn_s_barrier();
    __builtin_amdgcn_sched_barrier(0);
    #pragma unroll
    for (int ksub = 0; ksub < 2; ++ksub) {
      const int soff = ((ksub * 4 + q) ^ rlow) * 8;    // B swizzled slot
      const int g0 = (ksub * 4 + q) * 2;               // A group pair
      short8v af[4], bf[4];
      #pragma unroll
      for (int mi = 0; mi < 4; ++mi) {
        const int row = wr * 64 + mi * 16 + (lane & 15);
        short4v lo = *(const short4v*)(&Als[cur][g0 * 512 + row * 4]);
        short4v hi = *(const short4v*)(&Als[cur][(g0 + 1) * 512 + row * 4]);
        af[mi][0] = lo[0]; af[mi][1] = lo[1]; af[mi][2] = lo[2]; af[mi][3] = lo[3];
        af[mi][4] = hi[0]; af[mi][5] = hi[1]; af[mi][6] = hi[2]; af[mi][7] = hi[3];
      }
      #pragma unroll
      for (int ni = 0; ni < 4; ++ni)
        bf[ni] = *(const short8v*)(&Bls[cur][(wc * 64 + ni * 16 + (lane & 15)) * 64 + soff]);
      #pragma unroll
      for (int mi = 0; mi < 4; ++mi)
        #pragma unroll
        for (int ni = 0; ni < 4; ++ni)
          acc[mi][ni] = __builtin_amdgcn_mfma_f32_16x16x32_bf16(af[mi], bf[ni], acc[mi][ni], 0, 0, 0);
    }
    cur ^= 1;
  }
  #undef STAGE

  // epilogue: out = acc + x*D  (C/D layout: col=lane&15, row=(lane>>4)*4+r)
  #pragma unroll
  for (int ni = 0; ni < 4; ++ni) {
    const int col = n0 + wc * 64 + ni * 16 + (lane & 15);
    const float dcol = Dv[col];
    #pragma unroll
    for (int mi = 0; mi < 4; ++mi) {
      #pragma unroll
      for (int r = 0; r < 4; ++r) {
        const int row = m0 + wr * 64 + mi * 16 + (lane >> 4) * 4 + r;
        const size_t idx = (size_t)row * 768 + col;
        out[idx] = acc[mi][ni][r] + x[idx] * dcol;
      }
    }
  }
}

// ---------------------------------------------------------------------------
extern "C" void kernel_launch(void* const* d_in, const int* in_sizes, int n_in,
                              void* d_out, int out_size, void* d_ws, size_t ws_size,
                              hipStream_t stream) {
  const float* x     = (const float*)d_in[0];
  const float* Wg    = (const float*)d_in[1];
  const float* bg    = (const float*)d_in[2];
  const float* alpha = (const float*)d_in[3];
  const float* beta  = (const float*)d_in[4];
  const float* Wout  = (const float*)d_in[5];
  const float* Dv    = (const float*)d_in[6];
  const int*   kp    = (const int*)d_in[7];
  float* out = (float*)d_out;

  // workspace layout (~195 MiB)
  //   partial aliases A_blk (partial dead after pool_reduce, before pde)
  //   xT is SEPARATE from A_blk (pde reads xT while writing A_blk)
  char* ws = (char*)d_ws;
  unsigned short* Ablk = (unsigned short*)(ws);                // 8*384*4096*4*2 = 100663296
  float* partial       = (float*)(ws);                         // 64*8*768*4 (alias Ablk)
  float* xT            = (float*)(ws + 100663296);             // 8*768*4096*4   = 100663296
  unsigned short* Wb   = (unsigned short*)(ws + 201326592);    // 768*1536*2     = 2359296
  float* pooled        = (float*)(ws + 203685888);             // 6144*4
  float* gam           = (float*)(ws + 203710464);             // 6144*4

  transpose_x_kernel<<<dim3(12, 64, 8), 256, 0, stream>>>(x, xT, partial);
  pool_reduce_kernel<<<24, 256, 0, stream>>>(partial, pooled);
  gamma_kernel<<<1536, 256, 0, stream>>>(pooled, Wg, bg, gam);
  cvt_bf16_kernel<<<(768 * 1536 + 255) / 256, 256, 0, stream>>>(Wout, Wb, 768 * 1536);
  pde_kernel<<<1536, 256, 0, stream>>>(xT, gam, alpha, beta, kp, Ablk);
  gemm_kernel<<<1536, 256, 0, stream>>>(Ablk, Wb, x, Dv, out);
}

// Round 20
// 452.925 us; speedup vs baseline: 1.1971x; 1.1971x over previous
//
#include <hip/hip_runtime.h>
#include <hip/hip_bf16.h>
#include <math.h>

// ---------------------------------------------------------------------------
// RealSymplecticReactionDiffusion2D — round 19
//  = R17 verified-best structure (310.5us), ONE isolated change:
//    pde blocks 256 -> 64 threads (1 wave), grid 1536 -> 6144,
//    __launch_bounds__(64,3).  Waves are independent (no LDS/barriers), so
//    1-wave blocks pack fractionally per CU (R18 counters showed only ~1
//    4-wave block resident -> TLP starvation).
// Stages:
//  1) transpose_x (FUSED pool partials) -> xT + partial
//  2) pool_reduce -> pooled[8][768]
//  3) gamma_kernel -> gamma[8][768]
//  4) cvt_bf16 (W_out -> bf16)
//  5) pde_kernel: ONE WAVE per (b,c) channel — 8x8 lane grid, 8x8 register
//     patch; halo via 32 shfls; no LDS/barriers.
//  6) transpose_uv -> A [32768][1536] bf16
//  7) gemm_kernel: 128x128 BK=64, 2-buf LDS, vmcnt(8), XOR swizzle,
//     XCD remap (~140us, 4x-verified)
//  Aliases: xT ~ A  (xT dead before A written); partial ~ uv (dead before pde)
// ---------------------------------------------------------------------------

typedef __attribute__((ext_vector_type(8))) short short8v;
typedef __attribute__((ext_vector_type(4))) float float4v;

static __device__ __forceinline__ unsigned short f2bf(float f) {
  unsigned u = __builtin_bit_cast(unsigned, f);
  u += 0x7FFFu + ((u >> 16) & 1u);   // round-to-nearest-even
  return (unsigned short)(u >> 16);
}

static __device__ __forceinline__ float softplusf(float x) {
  return (x > 20.0f) ? x : log1pf(expf(x));
}

// ---------------- transpose x [B,N,768] -> xT [B,768,N]  (+ pool partials) --
__global__ __launch_bounds__(256) void transpose_x_kernel(const float* __restrict__ x,
                                                          float* __restrict__ xT,
                                                          float* __restrict__ partial) {
  __shared__ float tile[64][65];
  __shared__ float red[4][64];
  const int c0 = blockIdx.x * 64;   // 12 tiles
  const int n0 = blockIdx.y * 64;   // 64 tiles
  const int b  = blockIdx.z;        // 8
  const int tl = threadIdx.x & 63;
  const int tw = threadIdx.x >> 6;  // 0..3
  const float* src = x + ((size_t)b * 4096 + n0) * 768 + c0;
  float s = 0.0f;
  #pragma unroll
  for (int j = 0; j < 16; ++j) {
    const int n = j * 4 + tw;
    const float val = src[(size_t)n * 768 + tl];
    tile[n][tl] = val;
    s += val;
  }
  red[tw][tl] = s;
  __syncthreads();
  // partial[n-chunk][b][c] ; n-chunk = blockIdx.y (64 chunks)
  if (tw == 0) {
    partial[((size_t)blockIdx.y * 8 + b) * 768 + c0 + tl] =
        red[0][tl] + red[1][tl] + red[2][tl] + red[3][tl];
  }
  float* dst = xT + ((size_t)b * 768 + c0) * 4096 + n0;
  #pragma unroll
  for (int j = 0; j < 16; ++j) {
    const int cc = j * 4 + tw;
    dst[(size_t)cc * 4096 + tl] = tile[tl][cc];
  }
}

__global__ void pool_reduce_kernel(const float* __restrict__ partial, float* __restrict__ pooled) {
  const int idx = blockIdx.x * 256 + threadIdx.x;   // 0..6143 = b*768+c
  float s = 0.0f;
  #pragma unroll
  for (int j = 0; j < 64; ++j) s += partial[(size_t)j * 6144 + idx];
  pooled[idx] = s * (1.0f / 4096.0f);
}

// ---------------- diffusion gate ----------------
__global__ void gamma_kernel(const float* __restrict__ pooled, const float* __restrict__ Wg,
                             const float* __restrict__ bg, float* __restrict__ gamma) {
  const int lane = threadIdx.x & 63;
  const int w = threadIdx.x >> 6;
  const int o = blockIdx.x * 4 + w;
  const int b = o / 768;
  const int j = o - b * 768;
  const float* pr = pooled + b * 768;
  const float* wr = Wg + (size_t)j * 768;
  float s = 0.0f;
  #pragma unroll
  for (int c = lane; c < 768; c += 64) s += pr[c] * wr[c];
  #pragma unroll
  for (int off = 32; off > 0; off >>= 1) s += __shfl_down(s, off);
  if (lane == 0) {
    float gin = s + bg[j];
    gamma[o] = fminf(softplusf(gin), 0.05f);
  }
}

// ---------------- W_out -> bf16 ----------------
__global__ void cvt_bf16_kernel(const float* __restrict__ src, unsigned short* __restrict__ dst, int n) {
  int i = blockIdx.x * 256 + threadIdx.x;
  if (i < n) dst[i] = f2bf(src[i]);
}

// ---------------- symplectic reaction-diffusion PDE (wave-per-channel) ------
// 1-WAVE blocks (64 thr), grid 6144 = one block per (b,c). Code identical to
// the 310.5us-verified version with w==0. No LDS, no barriers.
__global__ __launch_bounds__(64, 3) void pde_kernel(
    const float* __restrict__ xT, const float* __restrict__ gamma,
    const float* __restrict__ alpha, const float* __restrict__ beta,
    const int* __restrict__ kp, unsigned short* __restrict__ uv) {
  const int lane = threadIdx.x;            // 0..63
  const int cidx = blockIdx.x;             // 0..6143
  const int b = cidx / 768;
  const int c = cidx - b * 768;
  const int lx = lane & 7;
  const int ly = lane >> 3;

  int ks = *kp; if (ks < 1) ks = 1;
  const float dt = 1.0f / (float)ks;
  const float hdt = 0.5f * dt;
  const float ae = 0.2f * tanhf(alpha[c]);
  const float be = fmaxf(softplusf(beta[c]), 1e-4f);
  const float g = gamma[b * 768 + c];
  const float c1n = -0.5f * dt * g;   // v -= c1*lap  ->  v += c1n*lap
  const float c2p = dt * g;

  const int laneL = (ly << 3) | ((lx + 7) & 7);
  const int laneR = (ly << 3) | ((lx + 1) & 7);
  const int laneU = (((ly + 7) & 7) << 3) | lx;   // holds rows above (row-1)
  const int laneD = (((ly + 1) & 7) << 3) | lx;   // holds rows below (row+1)

  float u[64], v[64];
  const float* xp = xT + ((size_t)b * 768 + c) * 4096;
  #pragma unroll
  for (int r = 0; r < 8; ++r) {
    const float4* src = (const float4*)(xp + (ly * 8 + r) * 64 + lx * 8);
    const float4 a0 = src[0], a1 = src[1];
    u[r * 8 + 0] = a0.x; u[r * 8 + 1] = a0.y; u[r * 8 + 2] = a0.z; u[r * 8 + 3] = a0.w;
    u[r * 8 + 4] = a1.x; u[r * 8 + 5] = a1.y; u[r * 8 + 6] = a1.z; u[r * 8 + 7] = a1.w;
  }
  #pragma unroll
  for (int i = 0; i < 64; ++i) v[i] = 0.0f;

  // G += COEF * lap(F): halo via 32 shfls, interior in-register.
  #define LAP_PHASE(F, G, COEF)                                               \
    {                                                                         \
      float lh[8], rh[8], uh[8], dh[8];                                       \
      _Pragma("unroll")                                                       \
      for (int r = 0; r < 8; ++r) {                                           \
        lh[r] = __shfl(F[r * 8 + 7], laneL);   /* left lane's right col  */   \
        rh[r] = __shfl(F[r * 8 + 0], laneR);   /* right lane's left col  */   \
        uh[r] = __shfl(F[56 + r], laneU);      /* up lane's bottom row, col r */ \
        dh[r] = __shfl(F[r], laneD);           /* down lane's top row, col r  */ \
      }                                                                       \
      _Pragma("unroll")                                                       \
      for (int r = 0; r < 8; ++r) {                                           \
        _Pragma("unroll")                                                     \
        for (int j = 0; j < 8; ++j) {                                         \
          const float lf = (j == 0) ? lh[r] : F[r * 8 + j - 1];               \
          const float rt = (j == 7) ? rh[r] : F[r * 8 + j + 1];               \
          const float up = (r == 0) ? uh[j] : F[(r - 1) * 8 + j];             \
          const float dn = (r == 7) ? dh[j] : F[(r + 1) * 8 + j];             \
          const float lap = (lf + rt) + (up + dn) - 4.0f * F[r * 8 + j];      \
          G[r * 8 + j] = fmaf((COEF), lap, G[r * 8 + j]);                     \
        }                                                                     \
      }                                                                       \
    }

  for (int s = 0; s < ks; ++s) {
    #pragma unroll
    for (int i = 0; i < 64; ++i) {
      const float q = u[i] * u[i] + v[i] * v[i];
      const float rate = fminf(fmaxf(ae - be * q, -1.0f), 1.0f);
      const float t = hdt * rate;
      u[i] = fmaf(t, u[i], u[i]);
      v[i] = fmaf(t, v[i], v[i]);
    }
    LAP_PHASE(u, v, c1n)
    LAP_PHASE(v, u, c2p)
    LAP_PHASE(u, v, c1n)
    #pragma unroll
    for (int i = 0; i < 64; ++i) {
      const float q = u[i] * u[i] + v[i] * v[i];
      const float rate = fminf(fmaxf(ae - be * q, -1.0f), 1.0f);
      const float t = hdt * rate;
      u[i] = fmaf(t, u[i], u[i]);
      v[i] = fmaf(t, v[i], v[i]);
    }
  }
  #undef LAP_PHASE

  // write out channel-major bf16: uv[b][c][n] = u, uv[b][768+c][n] = v
  unsigned short* up_ = uv + ((size_t)b * 1536 + c) * 4096;
  unsigned short* vp_ = up_ + (size_t)768 * 4096;
  #pragma unroll
  for (int r = 0; r < 8; ++r) {
    const int off = (ly * 8 + r) * 64 + lx * 8;
    short8v us, vs;
    #pragma unroll
    for (int j = 0; j < 8; ++j) {
      us[j] = (short)f2bf(u[r * 8 + j]);
      vs[j] = (short)f2bf(v[r * 8 + j]);
    }
    *(short8v*)(up_ + off) = us;
    *(short8v*)(vp_ + off) = vs;
  }
}

// ---------------- transpose uv [8][1536][4096] -> A [32768][1536] ----------------
__global__ void transpose_uv_kernel(const unsigned short* __restrict__ src,
                                    unsigned short* __restrict__ dst) {
  // grid (64, 24, 8), block 256
  __shared__ unsigned short tile[64][66];
  const int n0 = blockIdx.x * 64;
  const int k0 = blockIdx.y * 64;
  const int b = blockIdx.z;
  const int tx = threadIdx.x & 63;
  const int ty = threadIdx.x >> 6;   // 0..3
  const size_t sbase = ((size_t)b * 1536 + k0) * 4096 + n0;
  #pragma unroll
  for (int j = 0; j < 16; ++j) {
    const int k = ty + 4 * j;
    tile[k][tx] = src[sbase + (size_t)k * 4096 + tx];
  }
  __syncthreads();
  const size_t dbase = ((size_t)b * 4096 + n0) * 1536 + k0;
  #pragma unroll
  for (int j = 0; j < 16; ++j) {
    const int n = ty + 4 * j;
    dst[dbase + (size_t)n * 1536 + tx] = tile[tx][n];
  }
}

// ---------------- bf16 MFMA GEMM (4x-verified ~140us) -----------------------
__global__ __launch_bounds__(256) void gemm_kernel(
    const unsigned short* __restrict__ A,   // [32768][1536] bf16
    const unsigned short* __restrict__ Bt,  // [768][1536]  bf16 (W_out, B^T layout)
    const float* __restrict__ x,            // [32768][768]
    const float* __restrict__ Dv,           // [768]
    float* __restrict__ out) {              // [32768][768]
  __shared__ __align__(16) unsigned short Als[2][128 * 64];
  __shared__ __align__(16) unsigned short Bls[2][128 * 64];
  const int tid = threadIdx.x;
  const int lane = tid & 63;
  const int w = tid >> 6;       // wave 0..3
  const int wr = w >> 1;        // wave row (2x2 waves, each 64x64 of C)
  const int wc = w & 1;

  // XCD-chunked remap: id -> (m-block, n-block). 1536 blocks, 8 XCDs.
  const int id = blockIdx.x;
  const int xcd = id & 7;
  const int seq = id >> 3;          // 0..191
  const int nb = seq % 6;
  const int mb = (seq / 6) * 8 + xcd;
  const int m0 = mb * 128;
  const int n0 = nb * 128;

  // staging-side swizzle: lane covers row (lane>>3), phys slot (lane&7);
  // load global logical slot (lane&7)^(lane>>3)
  const int src_col = (((lane & 7) ^ (lane >> 3)) * 8);   // halfwords
  // read-side: quarter-wave q, row-low bits rlow
  const int q = lane >> 4;
  const int rlow = lane & 7;

  float4v acc[4][4];
  #pragma unroll
  for (int a = 0; a < 4; ++a)
    #pragma unroll
    for (int bq = 0; bq < 4; ++bq)
      acc[a][bq] = (float4v){0.f, 0.f, 0.f, 0.f};

  // per-wave: 8 global_load_lds (4 A + 4 B), 16B each
  #define STAGE(bufi, kbase)                                                  \
    _Pragma("unroll")                                                         \
    for (int i = 0; i < 4; ++i) {                                             \
      const int rowblk = (w * 4 + i) * 8;                                     \
      const int row = rowblk + (lane >> 3);                                   \
      const int kk = (kbase) + src_col;                                       \
      __builtin_amdgcn_global_load_lds(                                       \
          (const __attribute__((address_space(1))) void*)(A + (size_t)(m0 + row) * 1536 + kk), \
          (__attribute__((address_space(3))) void*)(&Als[bufi][rowblk * 64]), 16, 0, 0); \
      __builtin_amdgcn_global_load_lds(                                       \
          (const __attribute__((address_space(1))) void*)(Bt + (size_t)(n0 + row) * 1536 + kk), \
          (__attribute__((address_space(3))) void*)(&Bls[bufi][rowblk * 64]), 16, 0, 0); \
    }

  STAGE(0, 0)
  int cur = 0;
  for (int kt = 0; kt < 24; ++kt) {
    // bar1: all waves' reads of buf[cur^1] retired -> safe to re-stage
    __builtin_amdgcn_s_barrier();
    if (kt < 23) {
      STAGE(cur ^ 1, (kt + 1) * 64)
      asm volatile("s_waitcnt vmcnt(8)" ::: "memory");   // wait prev 8, keep new 8 in flight
    } else {
      asm volatile("s_waitcnt vmcnt(0)" ::: "memory");   // last tile: drain
    }
    // bar2: every wave has its current buffer's loads complete
    __builtin_amdgcn_s_barrier();
    __builtin_amdgcn_sched_barrier(0);
    #pragma unroll
    for (int ksub = 0; ksub < 2; ++ksub) {
      const int soff = ((ksub * 4 + q) ^ rlow) * 8;    // swizzled 16B slot (halfwords)
      short8v af[4], bf[4];
      #pragma unroll
      for (int mi = 0; mi < 4; ++mi)
        af[mi] = *(const short8v*)(&Als[cur][(wr * 64 + mi * 16 + (lane & 15)) * 64 + soff]);
      #pragma unroll
      for (int ni = 0; ni < 4; ++ni)
        bf[ni] = *(const short8v*)(&Bls[cur][(wc * 64 + ni * 16 + (lane & 15)) * 64 + soff]);
      #pragma unroll
      for (int mi = 0; mi < 4; ++mi)
        #pragma unroll
        for (int ni = 0; ni < 4; ++ni)
          acc[mi][ni] = __builtin_amdgcn_mfma_f32_16x16x32_bf16(af[mi], bf[ni], acc[mi][ni], 0, 0, 0);
    }
    cur ^= 1;
  }
  #undef STAGE

  // epilogue: out = acc + x*D  (C/D layout: col=lane&15, row=(lane>>4)*4+r)
  #pragma unroll
  for (int ni = 0; ni < 4; ++ni) {
    const int col = n0 + wc * 64 + ni * 16 + (lane & 15);
    const float dcol = Dv[col];
    #pragma unroll
    for (int mi = 0; mi < 4; ++mi) {
      #pragma unroll
      for (int r = 0; r < 4; ++r) {
        const int row = m0 + wr * 64 + mi * 16 + (lane >> 4) * 4 + r;
        const size_t idx = (size_t)row * 768 + col;
        out[idx] = acc[mi][ni][r] + x[idx] * dcol;
      }
    }
  }
}

// ---------------------------------------------------------------------------
extern "C" void kernel_launch(void* const* d_in, const int* in_sizes, int n_in,
                              void* d_out, int out_size, void* d_ws, size_t ws_size,
                              hipStream_t stream) {
  const float* x     = (const float*)d_in[0];
  const float* Wg    = (const float*)d_in[1];
  const float* bg    = (const float*)d_in[2];
  const float* alpha = (const float*)d_in[3];
  const float* beta  = (const float*)d_in[4];
  const float* Wout  = (const float*)d_in[5];
  const float* Dv    = (const float*)d_in[6];
  const int*   kp    = (const int*)d_in[7];
  float* out = (float*)d_out;

  // workspace layout (~195 MiB)
  //   xT  aliases A   (xT dead before A is written by transpose_uv)
  //   partial aliases uv (partial consumed by pool_reduce before pde writes uv)
  char* ws = (char*)d_ws;
  unsigned short* A   = (unsigned short*)(ws);                 // 32768*1536*2   = 100663296
  float* xT           = (float*)(ws);                          // 8*768*4096*4   (alias A)
  unsigned short* uv  = (unsigned short*)(ws + 100663296);     // 8*1536*4096*2  = 100663296
  float* partial      = (float*)(ws + 100663296);              // 64*8*768*4     (alias uv)
  unsigned short* Wb  = (unsigned short*)(ws + 201326592);     // 768*1536*2     = 2359296
  float* pooled       = (float*)(ws + 203685888);              // 6144*4
  float* gam          = (float*)(ws + 203710464);              // 6144*4

  transpose_x_kernel<<<dim3(12, 64, 8), 256, 0, stream>>>(x, xT, partial);
  pool_reduce_kernel<<<24, 256, 0, stream>>>(partial, pooled);
  gamma_kernel<<<1536, 256, 0, stream>>>(pooled, Wg, bg, gam);
  cvt_bf16_kernel<<<(768 * 1536 + 255) / 256, 256, 0, stream>>>(Wout, Wb, 768 * 1536);
  pde_kernel<<<6144, 64, 0, stream>>>(xT, gam, alpha, beta, kp, uv);
  transpose_uv_kernel<<<dim3(64, 24, 8), 256, 0, stream>>>(uv, A);
  gemm_kernel<<<1536, 256, 0, stream>>>(A, Wb, x, Dv, out);
}

// Round 21
// 310.072 us; speedup vs baseline: 1.7487x; 1.4607x over previous
//
#include <hip/hip_runtime.h>
#include <hip/hip_bf16.h>
#include <math.h>

// ---------------------------------------------------------------------------
// RealSymplecticReactionDiffusion2D — round 20 = R17 verified-best (310.5us)
//  B=8, N=4096 (64x64), d=768, k_steps=4 (read from device)
// Stages:
//  1) transpose_x (FUSED column-sum partials for mean-pool) -> xT + partial
//  2) pool_reduce  -> pooled[8][768]
//  3) gamma_kernel -> gamma[8][768]
//  4) cvt_bf16 (W_out -> bf16)
//  5) pde_kernel: ONE WAVE per (b,c) channel — 8x8 lane grid, 8x8 register
//     patch per lane; halo via 32 shfls; no LDS/barriers. (256,1): no-spill
//     codegen (VGPR 148). [R19 lesson: 64-thr blocks spill -> 718MB scratch]
//  6) transpose_uv -> A [32768][1536] bf16
//  7) gemm_kernel: 128x128 tile BK=64, 2-buf LDS, counted vmcnt(8),
//     XOR swizzle (conflict=0), XCD remap  (~140us, 4x-verified; within
//     ~10% of the 2-phase structural ceiling)
//  Aliases: xT ~ A  (xT dead before A written); partial ~ uv (dead before pde)
// ---------------------------------------------------------------------------

typedef __attribute__((ext_vector_type(8))) short short8v;
typedef __attribute__((ext_vector_type(4))) float float4v;

static __device__ __forceinline__ unsigned short f2bf(float f) {
  unsigned u = __builtin_bit_cast(unsigned, f);
  u += 0x7FFFu + ((u >> 16) & 1u);   // round-to-nearest-even
  return (unsigned short)(u >> 16);
}

static __device__ __forceinline__ float softplusf(float x) {
  return (x > 20.0f) ? x : log1pf(expf(x));
}

// ---------------- transpose x [B,N,768] -> xT [B,768,N]  (+ pool partials) --
__global__ __launch_bounds__(256) void transpose_x_kernel(const float* __restrict__ x,
                                                          float* __restrict__ xT,
                                                          float* __restrict__ partial) {
  __shared__ float tile[64][65];
  __shared__ float red[4][64];
  const int c0 = blockIdx.x * 64;   // 12 tiles
  const int n0 = blockIdx.y * 64;   // 64 tiles
  const int b  = blockIdx.z;        // 8
  const int tl = threadIdx.x & 63;
  const int tw = threadIdx.x >> 6;  // 0..3
  const float* src = x + ((size_t)b * 4096 + n0) * 768 + c0;
  float s = 0.0f;
  #pragma unroll
  for (int j = 0; j < 16; ++j) {
    const int n = j * 4 + tw;
    const float val = src[(size_t)n * 768 + tl];
    tile[n][tl] = val;
    s += val;
  }
  red[tw][tl] = s;
  __syncthreads();
  // partial[n-chunk][b][c] ; n-chunk = blockIdx.y (64 chunks)
  if (tw == 0) {
    partial[((size_t)blockIdx.y * 8 + b) * 768 + c0 + tl] =
        red[0][tl] + red[1][tl] + red[2][tl] + red[3][tl];
  }
  float* dst = xT + ((size_t)b * 768 + c0) * 4096 + n0;
  #pragma unroll
  for (int j = 0; j < 16; ++j) {
    const int cc = j * 4 + tw;
    dst[(size_t)cc * 4096 + tl] = tile[tl][cc];
  }
}

__global__ void pool_reduce_kernel(const float* __restrict__ partial, float* __restrict__ pooled) {
  const int idx = blockIdx.x * 256 + threadIdx.x;   // 0..6143 = b*768+c
  float s = 0.0f;
  #pragma unroll
  for (int j = 0; j < 64; ++j) s += partial[(size_t)j * 6144 + idx];
  pooled[idx] = s * (1.0f / 4096.0f);
}

// ---------------- diffusion gate ----------------
__global__ void gamma_kernel(const float* __restrict__ pooled, const float* __restrict__ Wg,
                             const float* __restrict__ bg, float* __restrict__ gamma) {
  const int lane = threadIdx.x & 63;
  const int w = threadIdx.x >> 6;
  const int o = blockIdx.x * 4 + w;
  const int b = o / 768;
  const int j = o - b * 768;
  const float* pr = pooled + b * 768;
  const float* wr = Wg + (size_t)j * 768;
  float s = 0.0f;
  #pragma unroll
  for (int c = lane; c < 768; c += 64) s += pr[c] * wr[c];
  #pragma unroll
  for (int off = 32; off > 0; off >>= 1) s += __shfl_down(s, off);
  if (lane == 0) {
    float gin = s + bg[j];
    gamma[o] = fminf(softplusf(gin), 0.05f);
  }
}

// ---------------- W_out -> bf16 ----------------
__global__ void cvt_bf16_kernel(const float* __restrict__ src, unsigned short* __restrict__ dst, int n) {
  int i = blockIdx.x * 256 + threadIdx.x;
  if (i < n) dst[i] = f2bf(src[i]);
}

// ---------------- symplectic reaction-diffusion PDE (wave-per-channel) ------
__global__ __launch_bounds__(256, 1) void pde_kernel(
    const float* __restrict__ xT, const float* __restrict__ gamma,
    const float* __restrict__ alpha, const float* __restrict__ beta,
    const int* __restrict__ kp, unsigned short* __restrict__ uv) {
  const int w = threadIdx.x >> 6;          // wave 0..3 (independent channels)
  const int lane = threadIdx.x & 63;
  const int cidx = blockIdx.x * 4 + w;     // 0..6143
  const int b = cidx / 768;
  const int c = cidx - b * 768;
  const int lx = lane & 7;
  const int ly = lane >> 3;

  int ks = *kp; if (ks < 1) ks = 1;
  const float dt = 1.0f / (float)ks;
  const float hdt = 0.5f * dt;
  const float ae = 0.2f * tanhf(alpha[c]);
  const float be = fmaxf(softplusf(beta[c]), 1e-4f);
  const float g = gamma[b * 768 + c];
  const float c1n = -0.5f * dt * g;   // v -= c1*lap  ->  v += c1n*lap
  const float c2p = dt * g;

  const int laneL = (ly << 3) | ((lx + 7) & 7);
  const int laneR = (ly << 3) | ((lx + 1) & 7);
  const int laneU = (((ly + 7) & 7) << 3) | lx;   // holds rows above (row-1)
  const int laneD = (((ly + 1) & 7) << 3) | lx;   // holds rows below (row+1)

  float u[64], v[64];
  const float* xp = xT + ((size_t)b * 768 + c) * 4096;
  #pragma unroll
  for (int r = 0; r < 8; ++r) {
    const float4* src = (const float4*)(xp + (ly * 8 + r) * 64 + lx * 8);
    const float4 a0 = src[0], a1 = src[1];
    u[r * 8 + 0] = a0.x; u[r * 8 + 1] = a0.y; u[r * 8 + 2] = a0.z; u[r * 8 + 3] = a0.w;
    u[r * 8 + 4] = a1.x; u[r * 8 + 5] = a1.y; u[r * 8 + 6] = a1.z; u[r * 8 + 7] = a1.w;
  }
  #pragma unroll
  for (int i = 0; i < 64; ++i) v[i] = 0.0f;

  // G += COEF * lap(F): halo via 32 shfls, interior in-register.
  #define LAP_PHASE(F, G, COEF)                                               \
    {                                                                         \
      float lh[8], rh[8], uh[8], dh[8];                                       \
      _Pragma("unroll")                                                       \
      for (int r = 0; r < 8; ++r) {                                           \
        lh[r] = __shfl(F[r * 8 + 7], laneL);   /* left lane's right col  */   \
        rh[r] = __shfl(F[r * 8 + 0], laneR);   /* right lane's left col  */   \
        uh[r] = __shfl(F[56 + r], laneU);      /* up lane's bottom row, col r */ \
        dh[r] = __shfl(F[r], laneD);           /* down lane's top row, col r  */ \
      }                                                                       \
      _Pragma("unroll")                                                       \
      for (int r = 0; r < 8; ++r) {                                           \
        _Pragma("unroll")                                                     \
        for (int j = 0; j < 8; ++j) {                                         \
          const float lf = (j == 0) ? lh[r] : F[r * 8 + j - 1];               \
          const float rt = (j == 7) ? rh[r] : F[r * 8 + j + 1];               \
          const float up = (r == 0) ? uh[j] : F[(r - 1) * 8 + j];             \
          const float dn = (r == 7) ? dh[j] : F[(r + 1) * 8 + j];             \
          const float lap = (lf + rt) + (up + dn) - 4.0f * F[r * 8 + j];      \
          G[r * 8 + j] = fmaf((COEF), lap, G[r * 8 + j]);                     \
        }                                                                     \
      }                                                                       \
    }

  for (int s = 0; s < ks; ++s) {
    #pragma unroll
    for (int i = 0; i < 64; ++i) {
      const float q = u[i] * u[i] + v[i] * v[i];
      const float rate = fminf(fmaxf(ae - be * q, -1.0f), 1.0f);
      const float t = hdt * rate;
      u[i] = fmaf(t, u[i], u[i]);
      v[i] = fmaf(t, v[i], v[i]);
    }
    LAP_PHASE(u, v, c1n)
    LAP_PHASE(v, u, c2p)
    LAP_PHASE(u, v, c1n)
    #pragma unroll
    for (int i = 0; i < 64; ++i) {
      const float q = u[i] * u[i] + v[i] * v[i];
      const float rate = fminf(fmaxf(ae - be * q, -1.0f), 1.0f);
      const float t = hdt * rate;
      u[i] = fmaf(t, u[i], u[i]);
      v[i] = fmaf(t, v[i], v[i]);
    }
  }
  #undef LAP_PHASE

  // write out channel-major bf16: uv[b][c][n] = u, uv[b][768+c][n] = v
  unsigned short* up_ = uv + ((size_t)b * 1536 + c) * 4096;
  unsigned short* vp_ = up_ + (size_t)768 * 4096;
  #pragma unroll
  for (int r = 0; r < 8; ++r) {
    const int off = (ly * 8 + r) * 64 + lx * 8;
    short8v us, vs;
    #pragma unroll
    for (int j = 0; j < 8; ++j) {
      us[j] = (short)f2bf(u[r * 8 + j]);
      vs[j] = (short)f2bf(v[r * 8 + j]);
    }
    *(short8v*)(up_ + off) = us;
    *(short8v*)(vp_ + off) = vs;
  }
}

// ---------------- transpose uv [8][1536][4096] -> A [32768][1536] ----------------
__global__ void transpose_uv_kernel(const unsigned short* __restrict__ src,
                                    unsigned short* __restrict__ dst) {
  // grid (64, 24, 8), block 256
  __shared__ unsigned short tile[64][66];
  const int n0 = blockIdx.x * 64;
  const int k0 = blockIdx.y * 64;
  const int b = blockIdx.z;
  const int tx = threadIdx.x & 63;
  const int ty = threadIdx.x >> 6;   // 0..3
  const size_t sbase = ((size_t)b * 1536 + k0) * 4096 + n0;
  #pragma unroll
  for (int j = 0; j < 16; ++j) {
    const int k = ty + 4 * j;
    tile[k][tx] = src[sbase + (size_t)k * 4096 + tx];
  }
  __syncthreads();
  const size_t dbase = ((size_t)b * 4096 + n0) * 1536 + k0;
  #pragma unroll
  for (int j = 0; j < 16; ++j) {
    const int n = ty + 4 * j;
    dst[dbase + (size_t)n * 1536 + tx] = tile[tx][n];
  }
}

// ---------------- bf16 MFMA GEMM (4x-verified ~140us) -----------------------
__global__ __launch_bounds__(256) void gemm_kernel(
    const unsigned short* __restrict__ A,   // [32768][1536] bf16
    const unsigned short* __restrict__ Bt,  // [768][1536]  bf16 (W_out, B^T layout)
    const float* __restrict__ x,            // [32768][768]
    const float* __restrict__ Dv,           // [768]
    float* __restrict__ out) {              // [32768][768]
  __shared__ __align__(16) unsigned short Als[2][128 * 64];
  __shared__ __align__(16) unsigned short Bls[2][128 * 64];
  const int tid = threadIdx.x;
  const int lane = tid & 63;
  const int w = tid >> 6;       // wave 0..3
  const int wr = w >> 1;        // wave row (2x2 waves, each 64x64 of C)
  const int wc = w & 1;

  // XCD-chunked remap: id -> (m-block, n-block). 1536 blocks, 8 XCDs.
  const int id = blockIdx.x;
  const int xcd = id & 7;
  const int seq = id >> 3;          // 0..191
  const int nb = seq % 6;
  const int mb = (seq / 6) * 8 + xcd;
  const int m0 = mb * 128;
  const int n0 = nb * 128;

  // staging-side swizzle: lane covers row (lane>>3), phys slot (lane&7);
  // load global logical slot (lane&7)^(lane>>3)
  const int src_col = (((lane & 7) ^ (lane >> 3)) * 8);   // halfwords
  // read-side: quarter-wave q, row-low bits rlow
  const int q = lane >> 4;
  const int rlow = lane & 7;

  float4v acc[4][4];
  #pragma unroll
  for (int a = 0; a < 4; ++a)
    #pragma unroll
    for (int bq = 0; bq < 4; ++bq)
      acc[a][bq] = (float4v){0.f, 0.f, 0.f, 0.f};

  // per-wave: 8 global_load_lds (4 A + 4 B), 16B each
  #define STAGE(bufi, kbase)                                                  \
    _Pragma("unroll")                                                         \
    for (int i = 0; i < 4; ++i) {                                             \
      const int rowblk = (w * 4 + i) * 8;                                     \
      const int row = rowblk + (lane >> 3);                                   \
      const int kk = (kbase) + src_col;                                       \
      __builtin_amdgcn_global_load_lds(                                       \
          (const __attribute__((address_space(1))) void*)(A + (size_t)(m0 + row) * 1536 + kk), \
          (__attribute__((address_space(3))) void*)(&Als[bufi][rowblk * 64]), 16, 0, 0); \
      __builtin_amdgcn_global_load_lds(                                       \
          (const __attribute__((address_space(1))) void*)(Bt + (size_t)(n0 + row) * 1536 + kk), \
          (__attribute__((address_space(3))) void*)(&Bls[bufi][rowblk * 64]), 16, 0, 0); \
    }

  STAGE(0, 0)
  int cur = 0;
  for (int kt = 0; kt < 24; ++kt) {
    // bar1: all waves' reads of buf[cur^1] retired -> safe to re-stage
    __builtin_amdgcn_s_barrier();
    if (kt < 23) {
      STAGE(cur ^ 1, (kt + 1) * 64)
      asm volatile("s_waitcnt vmcnt(8)" ::: "memory");   // wait prev 8, keep new 8 in flight
    } else {
      asm volatile("s_waitcnt vmcnt(0)" ::: "memory");   // last tile: drain
    }
    // bar2: every wave has its current buffer's loads complete
    __builtin_amdgcn_s_barrier();
    __builtin_amdgcn_sched_barrier(0);
    #pragma unroll
    for (int ksub = 0; ksub < 2; ++ksub) {
      const int soff = ((ksub * 4 + q) ^ rlow) * 8;    // swizzled 16B slot (halfwords)
      short8v af[4], bf[4];
      #pragma unroll
      for (int mi = 0; mi < 4; ++mi)
        af[mi] = *(const short8v*)(&Als[cur][(wr * 64 + mi * 16 + (lane & 15)) * 64 + soff]);
      #pragma unroll
      for (int ni = 0; ni < 4; ++ni)
        bf[ni] = *(const short8v*)(&Bls[cur][(wc * 64 + ni * 16 + (lane & 15)) * 64 + soff]);
      #pragma unroll
      for (int mi = 0; mi < 4; ++mi)
        #pragma unroll
        for (int ni = 0; ni < 4; ++ni)
          acc[mi][ni] = __builtin_amdgcn_mfma_f32_16x16x32_bf16(af[mi], bf[ni], acc[mi][ni], 0, 0, 0);
    }
    cur ^= 1;
  }
  #undef STAGE

  // epilogue: out = acc + x*D  (C/D layout: col=lane&15, row=(lane>>4)*4+r)
  #pragma unroll
  for (int ni = 0; ni < 4; ++ni) {
    const int col = n0 + wc * 64 + ni * 16 + (lane & 15);
    const float dcol = Dv[col];
    #pragma unroll
    for (int mi = 0; mi < 4; ++mi) {
      #pragma unroll
      for (int r = 0; r < 4; ++r) {
        const int row = m0 + wr * 64 + mi * 16 + (lane >> 4) * 4 + r;
        const size_t idx = (size_t)row * 768 + col;
        out[idx] = acc[mi][ni][r] + x[idx] * dcol;
      }
    }
  }
}

// ---------------------------------------------------------------------------
extern "C" void kernel_launch(void* const* d_in, const int* in_sizes, int n_in,
                              void* d_out, int out_size, void* d_ws, size_t ws_size,
                              hipStream_t stream) {
  const float* x     = (const float*)d_in[0];
  const float* Wg    = (const float*)d_in[1];
  const float* bg    = (const float*)d_in[2];
  const float* alpha = (const float*)d_in[3];
  const float* beta  = (const float*)d_in[4];
  const float* Wout  = (const float*)d_in[5];
  const float* Dv    = (const float*)d_in[6];
  const int*   kp    = (const int*)d_in[7];
  float* out = (float*)d_out;

  // workspace layout (~195 MiB)
  //   xT  aliases A   (xT dead before A is written by transpose_uv)
  //   partial aliases uv (partial consumed by pool_reduce before pde writes uv)
  char* ws = (char*)d_ws;
  unsigned short* A   = (unsigned short*)(ws);                 // 32768*1536*2   = 100663296
  float* xT           = (float*)(ws);                          // 8*768*4096*4   (alias A)
  unsigned short* uv  = (unsigned short*)(ws + 100663296);     // 8*1536*4096*2  = 100663296
  float* partial      = (float*)(ws + 100663296);              // 64*8*768*4     (alias uv)
  unsigned short* Wb  = (unsigned short*)(ws + 201326592);     // 768*1536*2     = 2359296
  float* pooled       = (float*)(ws + 203685888);              // 6144*4
  float* gam          = (float*)(ws + 203710464);              // 6144*4

  transpose_x_kernel<<<dim3(12, 64, 8), 256, 0, stream>>>(x, xT, partial);
  pool_reduce_kernel<<<24, 256, 0, stream>>>(partial, pooled);
  gamma_kernel<<<1536, 256, 0, stream>>>(pooled, Wg, bg, gam);
  cvt_bf16_kernel<<<(768 * 1536 + 255) / 256, 256, 0, stream>>>(Wout, Wb, 768 * 1536);
  pde_kernel<<<1536, 256, 0, stream>>>(xT, gam, alpha, beta, kp, uv);
  transpose_uv_kernel<<<dim3(64, 24, 8), 256, 0, stream>>>(uv, A);
  gemm_kernel<<<1536, 256, 0, stream>>>(A, Wb, x, Dv, out);
}

// Round 22
// 306.016 us; speedup vs baseline: 1.7719x; 1.0133x over previous
//
#include <hip/hip_runtime.h>
#include <hip/hip_bf16.h>
#include <math.h>

// ---------------------------------------------------------------------------
// RealSymplecticReactionDiffusion2D — round 21
//  B=8, N=4096 (64x64), d=768, k_steps=4 (read from device)
// Stages:
//  1) transpose_x (FUSED pool partials) -> xT + partial
//  2) pool_reduce -> pooled[8][768]
//  3) gamma_kernel -> gamma[8][768]
//  4) cvt_bf16 (W_out -> bf16)
//  5) pde_kernel: R17-verified wave-per-channel math; output now bounces
//     through a 32KB LDS buffer fld[4ch][4096n] (u then v) and writes
//     Ablk[b][g][n][4ch] with 128B/thread fully-coalesced stores.
//     [R18 lesson: direct scalar 2B stores -> 718MB write amplification;
//      this keeps >=16B-contiguous per-lane stores.]
//     transpose_uv ELIMINATED (-35us wall, -200MB HBM).
//  6) gemm_kernel: R18-VERIFIED A-from-Ablk variant (~137us): R7 skeleton
//     (2-buf BK=64, vmcnt(8), XCD remap, B-swizzle); A staged 1KB-contiguous,
//     frag = 2x ds_read_b64 at g*512+row*4 (bank-minimal, conflict-free).
//  Workspace (R18-verified layout): Ablk@0 (partial aliases it, dead before
//  pde); xT@96MB separate (pde reads xT while writing Ablk).
// ---------------------------------------------------------------------------

typedef __attribute__((ext_vector_type(8))) short short8v;
typedef __attribute__((ext_vector_type(4))) short short4v;
typedef __attribute__((ext_vector_type(4))) float float4v;

static __device__ __forceinline__ unsigned short f2bf(float f) {
  unsigned u = __builtin_bit_cast(unsigned, f);
  u += 0x7FFFu + ((u >> 16) & 1u);   // round-to-nearest-even
  return (unsigned short)(u >> 16);
}

static __device__ __forceinline__ float softplusf(float x) {
  return (x > 20.0f) ? x : log1pf(expf(x));
}

// ---------------- transpose x [B,N,768] -> xT [B,768,N]  (+ pool partials) --
__global__ __launch_bounds__(256) void transpose_x_kernel(const float* __restrict__ x,
                                                          float* __restrict__ xT,
                                                          float* __restrict__ partial) {
  __shared__ float tile[64][65];
  __shared__ float red[4][64];
  const int c0 = blockIdx.x * 64;   // 12 tiles
  const int n0 = blockIdx.y * 64;   // 64 tiles
  const int b  = blockIdx.z;        // 8
  const int tl = threadIdx.x & 63;
  const int tw = threadIdx.x >> 6;  // 0..3
  const float* src = x + ((size_t)b * 4096 + n0) * 768 + c0;
  float s = 0.0f;
  #pragma unroll
  for (int j = 0; j < 16; ++j) {
    const int n = j * 4 + tw;
    const float val = src[(size_t)n * 768 + tl];
    tile[n][tl] = val;
    s += val;
  }
  red[tw][tl] = s;
  __syncthreads();
  // partial[n-chunk][b][c] ; n-chunk = blockIdx.y (64 chunks)
  if (tw == 0) {
    partial[((size_t)blockIdx.y * 8 + b) * 768 + c0 + tl] =
        red[0][tl] + red[1][tl] + red[2][tl] + red[3][tl];
  }
  float* dst = xT + ((size_t)b * 768 + c0) * 4096 + n0;
  #pragma unroll
  for (int j = 0; j < 16; ++j) {
    const int cc = j * 4 + tw;
    dst[(size_t)cc * 4096 + tl] = tile[tl][cc];
  }
}

__global__ void pool_reduce_kernel(const float* __restrict__ partial, float* __restrict__ pooled) {
  const int idx = blockIdx.x * 256 + threadIdx.x;   // 0..6143 = b*768+c
  float s = 0.0f;
  #pragma unroll
  for (int j = 0; j < 64; ++j) s += partial[(size_t)j * 6144 + idx];
  pooled[idx] = s * (1.0f / 4096.0f);
}

// ---------------- diffusion gate ----------------
__global__ void gamma_kernel(const float* __restrict__ pooled, const float* __restrict__ Wg,
                             const float* __restrict__ bg, float* __restrict__ gamma) {
  const int lane = threadIdx.x & 63;
  const int w = threadIdx.x >> 6;
  const int o = blockIdx.x * 4 + w;
  const int b = o / 768;
  const int j = o - b * 768;
  const float* pr = pooled + b * 768;
  const float* wr = Wg + (size_t)j * 768;
  float s = 0.0f;
  #pragma unroll
  for (int c = lane; c < 768; c += 64) s += pr[c] * wr[c];
  #pragma unroll
  for (int off = 32; off > 0; off >>= 1) s += __shfl_down(s, off);
  if (lane == 0) {
    float gin = s + bg[j];
    gamma[o] = fminf(softplusf(gin), 0.05f);
  }
}

// ---------------- W_out -> bf16 ----------------
__global__ void cvt_bf16_kernel(const float* __restrict__ src, unsigned short* __restrict__ dst, int n) {
  int i = blockIdx.x * 256 + threadIdx.x;
  if (i < n) dst[i] = f2bf(src[i]);
}

// ---------------- symplectic reaction-diffusion PDE (wave-per-channel) ------
// R17-verified math/load. Output: LDS bounce fld[4][4096] (u then v) ->
// Ablk[b][g][n][4ch]; u -> group cg, v -> group 192+cg (cg = c0/4).
// Gather: thread t emits 128B contiguous (16 n x 4 ch), coalesced block-wide.
__global__ __launch_bounds__(256, 1) void pde_kernel(
    const float* __restrict__ xT, const float* __restrict__ gamma,
    const float* __restrict__ alpha, const float* __restrict__ beta,
    const int* __restrict__ kp, unsigned short* __restrict__ Ablk) {
  __shared__ __align__(16) unsigned short fld[4][4096];   // 32KB, reused u->v
  const int w = threadIdx.x >> 6;          // wave 0..3 -> channel c0+w
  const int lane = threadIdx.x & 63;
  const int t = threadIdx.x;
  const int b = blockIdx.x / 192;          // 1536 blocks = 8 b x 192 cgroups
  const int cg = blockIdx.x - b * 192;
  const int c = cg * 4 + w;
  const int lx = lane & 7;
  const int ly = lane >> 3;

  int ks = *kp; if (ks < 1) ks = 1;
  const float dt = 1.0f / (float)ks;
  const float hdt = 0.5f * dt;
  const float ae = 0.2f * tanhf(alpha[c]);
  const float be = fmaxf(softplusf(beta[c]), 1e-4f);
  const float g = gamma[b * 768 + c];
  const float c1n = -0.5f * dt * g;   // v -= c1*lap  ->  v += c1n*lap
  const float c2p = dt * g;

  const int laneL = (ly << 3) | ((lx + 7) & 7);
  const int laneR = (ly << 3) | ((lx + 1) & 7);
  const int laneU = (((ly + 7) & 7) << 3) | lx;   // holds rows above (row-1)
  const int laneD = (((ly + 1) & 7) << 3) | lx;   // holds rows below (row+1)

  float u[64], v[64];
  const float* xp = xT + ((size_t)b * 768 + c) * 4096;
  #pragma unroll
  for (int r = 0; r < 8; ++r) {
    const float4* src = (const float4*)(xp + (ly * 8 + r) * 64 + lx * 8);
    const float4 a0 = src[0], a1 = src[1];
    u[r * 8 + 0] = a0.x; u[r * 8 + 1] = a0.y; u[r * 8 + 2] = a0.z; u[r * 8 + 3] = a0.w;
    u[r * 8 + 4] = a1.x; u[r * 8 + 5] = a1.y; u[r * 8 + 6] = a1.z; u[r * 8 + 7] = a1.w;
  }
  #pragma unroll
  for (int i = 0; i < 64; ++i) v[i] = 0.0f;

  // G += COEF * lap(F): halo via 32 shfls, interior in-register.
  #define LAP_PHASE(F, G, COEF)                                               \
    {                                                                         \
      float lh[8], rh[8], uh[8], dh[8];                                       \
      _Pragma("unroll")                                                       \
      for (int r = 0; r < 8; ++r) {                                           \
        lh[r] = __shfl(F[r * 8 + 7], laneL);                                  \
        rh[r] = __shfl(F[r * 8 + 0], laneR);                                  \
        uh[r] = __shfl(F[56 + r], laneU);                                     \
        dh[r] = __shfl(F[r], laneD);                                          \
      }                                                                       \
      _Pragma("unroll")                                                       \
      for (int r = 0; r < 8; ++r) {                                           \
        _Pragma("unroll")                                                     \
        for (int j = 0; j < 8; ++j) {                                         \
          const float lf = (j == 0) ? lh[r] : F[r * 8 + j - 1];               \
          const float rt = (j == 7) ? rh[r] : F[r * 8 + j + 1];               \
          const float up = (r == 0) ? uh[j] : F[(r - 1) * 8 + j];             \
          const float dn = (r == 7) ? dh[j] : F[(r + 1) * 8 + j];             \
          const float lap = (lf + rt) + (up + dn) - 4.0f * F[r * 8 + j];      \
          G[r * 8 + j] = fmaf((COEF), lap, G[r * 8 + j]);                     \
        }                                                                     \
      }                                                                       \
    }

  for (int s = 0; s < ks; ++s) {
    #pragma unroll
    for (int i = 0; i < 64; ++i) {
      const float q = u[i] * u[i] + v[i] * v[i];
      const float rate = fminf(fmaxf(ae - be * q, -1.0f), 1.0f);
      const float tt = hdt * rate;
      u[i] = fmaf(tt, u[i], u[i]);
      v[i] = fmaf(tt, v[i], v[i]);
    }
    LAP_PHASE(u, v, c1n)
    LAP_PHASE(v, u, c2p)
    LAP_PHASE(u, v, c1n)
    #pragma unroll
    for (int i = 0; i < 64; ++i) {
      const float q = u[i] * u[i] + v[i] * v[i];
      const float rate = fminf(fmaxf(ae - be * q, -1.0f), 1.0f);
      const float tt = hdt * rate;
      u[i] = fmaf(tt, u[i], u[i]);
      v[i] = fmaf(tt, v[i], v[i]);
    }
  }
  #undef LAP_PHASE

  // ---- output: wave w -> fld[w] (same 16B store pattern as verified uv
  // write, but to LDS); barrier; coalesced gather to Ablk. u then v.
  #define DUMP(F, gbase)                                                      \
    {                                                                         \
      _Pragma("unroll")                                                       \
      for (int r = 0; r < 8; ++r) {                                           \
        short8v o;                                                            \
        _Pragma("unroll")                                                     \
        for (int j = 0; j < 8; ++j) o[j] = (short)f2bf(F[r * 8 + j]);         \
        *(short8v*)(&fld[w][(ly * 8 + r) * 64 + lx * 8]) = o;                 \
      }                                                                       \
      __syncthreads();                                                        \
      {                                                                       \
        unsigned short* ab = Ablk + (size_t)(b * 384 + (gbase) + cg) * 16384; \
        const int n0 = t * 16;                                                \
        _Pragma("unroll")                                                     \
        for (int grp = 0; grp < 4; ++grp) {                                   \
          const int nn = n0 + grp * 4;                                        \
          short4v s0 = *(const short4v*)(&fld[0][nn]);                        \
          short4v s1 = *(const short4v*)(&fld[1][nn]);                        \
          short4v s2 = *(const short4v*)(&fld[2][nn]);                        \
          short4v s3 = *(const short4v*)(&fld[3][nn]);                        \
          short8v o1, o2;                                                     \
          o1[0] = s0[0]; o1[1] = s1[0]; o1[2] = s2[0]; o1[3] = s3[0];         \
          o1[4] = s0[1]; o1[5] = s1[1]; o1[6] = s2[1]; o1[7] = s3[1];         \
          o2[0] = s0[2]; o2[1] = s1[2]; o2[2] = s2[2]; o2[3] = s3[2];         \
          o2[4] = s0[3]; o2[5] = s1[3]; o2[6] = s2[3]; o2[7] = s3[3];         \
          *(short8v*)(ab + (size_t)nn * 4) = o1;                              \
          *(short8v*)(ab + (size_t)nn * 4 + 8) = o2;                          \
        }                                                                     \
      }                                                                       \
      __syncthreads();                                                        \
    }

  DUMP(u, 0)
  DUMP(v, 192)
  #undef DUMP
}

// ---------------- bf16 MFMA GEMM (R18-verified A-from-Ablk, ~137us) ---------
// out = A @ W^T + x*D.  128x128 tile, BK=64 (=16 groups of 4ch), 2-buf LDS,
// vmcnt(8), XCD remap.  A LDS tile [16g][128n][4ch] (512 hw per g), staged
// 1KB-contiguous; frag = 2x ds_read_b64 at g*512+row*4 (conflict-free).
// B path/swizzle/epilogue R7-exact.
__global__ __launch_bounds__(256) void gemm_kernel(
    const unsigned short* __restrict__ Ablk, // [8][384][4096][4] bf16
    const unsigned short* __restrict__ Bt,   // [768][1536] bf16 (W_out)
    const float* __restrict__ x,             // [32768][768]
    const float* __restrict__ Dv,            // [768]
    float* __restrict__ out) {               // [32768][768]
  __shared__ __align__(16) unsigned short Als[2][128 * 64];
  __shared__ __align__(16) unsigned short Bls[2][128 * 64];
  const int tid = threadIdx.x;
  const int lane = tid & 63;
  const int w = tid >> 6;       // wave 0..3
  const int wr = w >> 1;        // wave row (2x2 waves, each 64x64 of C)
  const int wc = w & 1;

  // XCD-chunked remap: id -> (m-block, n-block). 1536 blocks, 8 XCDs.
  const int id = blockIdx.x;
  const int xcd = id & 7;
  const int seq = id >> 3;          // 0..191
  const int nb = seq % 6;
  const int mb = (seq / 6) * 8 + xcd;
  const int m0 = mb * 128;
  const int n0 = nb * 128;
  const int bb = m0 >> 12;          // batch of this m-panel
  const int nb0 = m0 & 4095;        // n offset within batch

  // B staging swizzle (R7): load global logical slot (lane&7)^(lane>>3)
  const int src_col = (((lane & 7) ^ (lane >> 3)) * 8);   // halfwords
  // read-side (B): quarter-wave q, row-low bits rlow
  const int q = lane >> 4;
  const int rlow = lane & 7;

  float4v acc[4][4];
  #pragma unroll
  for (int a = 0; a < 4; ++a)
    #pragma unroll
    for (int bq = 0; bq < 4; ++bq)
      acc[a][bq] = (float4v){0.f, 0.f, 0.f, 0.f};

  // per-wave: 4 A + 4 B global_load_lds, 16B each (vmcnt budget 8, as R7)
  #define STAGE(bufi, kt)                                                     \
    _Pragma("unroll")                                                         \
    for (int i = 0; i < 4; ++i) {                                             \
      const int g_off = w * 4 + i;          /* 0..15 */                       \
      __builtin_amdgcn_global_load_lds(                                       \
          (const __attribute__((address_space(1))) void*)(Ablk + ((size_t)(bb * 384 + (kt) * 16 + g_off) * 4096 + nb0) * 4 + lane * 8), \
          (__attribute__((address_space(3))) void*)(&Als[bufi][g_off * 512]), 16, 0, 0); \
      const int rowblk = g_off * 8;                                           \
      const int row = rowblk + (lane >> 3);                                   \
      __builtin_amdgcn_global_load_lds(                                       \
          (const __attribute__((address_space(1))) void*)(Bt + (size_t)(n0 + row) * 1536 + (kt) * 64 + src_col), \
          (__attribute__((address_space(3))) void*)(&Bls[bufi][rowblk * 64]), 16, 0, 0); \
    }

  STAGE(0, 0)
  int cur = 0;
  for (int kt = 0; kt < 24; ++kt) {
    // bar1: all waves' reads of buf[cur^1] retired -> safe to re-stage
    __builtin_amdgcn_s_barrier();
    if (kt < 23) {
      STAGE(cur ^ 1, kt + 1)
      asm volatile("s_waitcnt vmcnt(8)" ::: "memory");   // wait prev 8, keep new 8 in flight
    } else {
      asm volatile("s_waitcnt vmcnt(0)" ::: "memory");   // last tile: drain
    }
    // bar2: every wave has its current buffer's loads complete
    __builtin_amdgcn_s_barrier();
    __builtin_amdgcn_sched_barrier(0);
    #pragma unroll
    for (int ksub = 0; ksub < 2; ++ksub) {
      const int soff = ((ksub * 4 + q) ^ rlow) * 8;    // B swizzled slot
      const int g0 = (ksub * 4 + q) * 2;               // A group pair
      short8v af[4], bf[4];
      #pragma unroll
      for (int mi = 0; mi < 4; ++mi) {
        const int row = wr * 64 + mi * 16 + (lane & 15);
        short4v lo = *(const short4v*)(&Als[cur][g0 * 512 + row * 4]);
        short4v hi = *(const short4v*)(&Als[cur][(g0 + 1) * 512 + row * 4]);
        af[mi][0] = lo[0]; af[mi][1] = lo[1]; af[mi][2] = lo[2]; af[mi][3] = lo[3];
        af[mi][4] = hi[0]; af[mi][5] = hi[1]; af[mi][6] = hi[2]; af[mi][7] = hi[3];
      }
      #pragma unroll
      for (int ni = 0; ni < 4; ++ni)
        bf[ni] = *(const short8v*)(&Bls[cur][(wc * 64 + ni * 16 + (lane & 15)) * 64 + soff]);
      #pragma unroll
      for (int mi = 0; mi < 4; ++mi)
        #pragma unroll
        for (int ni = 0; ni < 4; ++ni)
          acc[mi][ni] = __builtin_amdgcn_mfma_f32_16x16x32_bf16(af[mi], bf[ni], acc[mi][ni], 0, 0, 0);
    }
    cur ^= 1;
  }
  #undef STAGE

  // epilogue: out = acc + x*D  (C/D layout: col=lane&15, row=(lane>>4)*4+r)
  #pragma unroll
  for (int ni = 0; ni < 4; ++ni) {
    const int col = n0 + wc * 64 + ni * 16 + (lane & 15);
    const float dcol = Dv[col];
    #pragma unroll
    for (int mi = 0; mi < 4; ++mi) {
      #pragma unroll
      for (int r = 0; r < 4; ++r) {
        const int row = m0 + wr * 64 + mi * 16 + (lane >> 4) * 4 + r;
        const size_t idx = (size_t)row * 768 + col;
        out[idx] = acc[mi][ni][r] + x[idx] * dcol;
      }
    }
  }
}

// ---------------------------------------------------------------------------
extern "C" void kernel_launch(void* const* d_in, const int* in_sizes, int n_in,
                              void* d_out, int out_size, void* d_ws, size_t ws_size,
                              hipStream_t stream) {
  const float* x     = (const float*)d_in[0];
  const float* Wg    = (const float*)d_in[1];
  const float* bg    = (const float*)d_in[2];
  const float* alpha = (const float*)d_in[3];
  const float* beta  = (const float*)d_in[4];
  const float* Wout  = (const float*)d_in[5];
  const float* Dv    = (const float*)d_in[6];
  const int*   kp    = (const int*)d_in[7];
  float* out = (float*)d_out;

  // workspace layout (~195 MiB, R18-verified)
  //   partial aliases A_blk (partial dead after pool_reduce, before pde)
  //   xT is SEPARATE from A_blk (pde reads xT while writing A_blk)
  char* ws = (char*)d_ws;
  unsigned short* Ablk = (unsigned short*)(ws);                // 8*384*4096*4*2 = 100663296
  float* partial       = (float*)(ws);                         // 64*8*768*4 (alias Ablk)
  float* xT            = (float*)(ws + 100663296);             // 8*768*4096*4   = 100663296
  unsigned short* Wb   = (unsigned short*)(ws + 201326592);    // 768*1536*2     = 2359296
  float* pooled        = (float*)(ws + 203685888);             // 6144*4
  float* gam           = (float*)(ws + 203710464);             // 6144*4

  transpose_x_kernel<<<dim3(12, 64, 8), 256, 0, stream>>>(x, xT, partial);
  pool_reduce_kernel<<<24, 256, 0, stream>>>(partial, pooled);
  gamma_kernel<<<1536, 256, 0, stream>>>(pooled, Wg, bg, gam);
  cvt_bf16_kernel<<<(768 * 1536 + 255) / 256, 256, 0, stream>>>(Wout, Wb, 768 * 1536);
  pde_kernel<<<1536, 256, 0, stream>>>(xT, gam, alpha, beta, kp, Ablk);
  gemm_kernel<<<1536, 256, 0, stream>>>(Ablk, Wb, x, Dv, out);
}

// Round 23
// 300.521 us; speedup vs baseline: 1.8043x; 1.0183x over previous
//
#include <hip/hip_runtime.h>
#include <hip/hip_bf16.h>
#include <math.h>

// ---------------------------------------------------------------------------
// RealSymplecticReactionDiffusion2D — round 22
//  = R21 (306.0us best), ONE change: DUMP gather re-indexed
//    nn = t*16+grp*4  ->  nn = grp*1024 + t*4
//    (old: 16-way LDS bank conflict on every 8B gather read + scattered
//     stores; new: conflict-free 4-lane/bank reads + 2KB-contiguous stores)
// Stages:
//  1) transpose_x (FUSED pool partials) -> xT + partial
//  2) pool_reduce -> pooled[8][768]
//  3) gamma_kernel -> gamma[8][768]
//  4) cvt_bf16 (W_out -> bf16)
//  5) pde_kernel: R17-verified wave-per-channel math; output via 32KB LDS
//     bounce fld[4ch][4096n] (u then v) -> Ablk[b][g][n][4ch] coalesced.
//  6) gemm_kernel: R18-verified A-from-Ablk (~140us), R7 skeleton.
//  Workspace: Ablk@0 (partial aliases, dead before pde); xT@96MB separate.
// ---------------------------------------------------------------------------

typedef __attribute__((ext_vector_type(8))) short short8v;
typedef __attribute__((ext_vector_type(4))) short short4v;
typedef __attribute__((ext_vector_type(4))) float float4v;

static __device__ __forceinline__ unsigned short f2bf(float f) {
  unsigned u = __builtin_bit_cast(unsigned, f);
  u += 0x7FFFu + ((u >> 16) & 1u);   // round-to-nearest-even
  return (unsigned short)(u >> 16);
}

static __device__ __forceinline__ float softplusf(float x) {
  return (x > 20.0f) ? x : log1pf(expf(x));
}

// ---------------- transpose x [B,N,768] -> xT [B,768,N]  (+ pool partials) --
__global__ __launch_bounds__(256) void transpose_x_kernel(const float* __restrict__ x,
                                                          float* __restrict__ xT,
                                                          float* __restrict__ partial) {
  __shared__ float tile[64][65];
  __shared__ float red[4][64];
  const int c0 = blockIdx.x * 64;   // 12 tiles
  const int n0 = blockIdx.y * 64;   // 64 tiles
  const int b  = blockIdx.z;        // 8
  const int tl = threadIdx.x & 63;
  const int tw = threadIdx.x >> 6;  // 0..3
  const float* src = x + ((size_t)b * 4096 + n0) * 768 + c0;
  float s = 0.0f;
  #pragma unroll
  for (int j = 0; j < 16; ++j) {
    const int n = j * 4 + tw;
    const float val = src[(size_t)n * 768 + tl];
    tile[n][tl] = val;
    s += val;
  }
  red[tw][tl] = s;
  __syncthreads();
  // partial[n-chunk][b][c] ; n-chunk = blockIdx.y (64 chunks)
  if (tw == 0) {
    partial[((size_t)blockIdx.y * 8 + b) * 768 + c0 + tl] =
        red[0][tl] + red[1][tl] + red[2][tl] + red[3][tl];
  }
  float* dst = xT + ((size_t)b * 768 + c0) * 4096 + n0;
  #pragma unroll
  for (int j = 0; j < 16; ++j) {
    const int cc = j * 4 + tw;
    dst[(size_t)cc * 4096 + tl] = tile[tl][cc];
  }
}

__global__ void pool_reduce_kernel(const float* __restrict__ partial, float* __restrict__ pooled) {
  const int idx = blockIdx.x * 256 + threadIdx.x;   // 0..6143 = b*768+c
  float s = 0.0f;
  #pragma unroll
  for (int j = 0; j < 64; ++j) s += partial[(size_t)j * 6144 + idx];
  pooled[idx] = s * (1.0f / 4096.0f);
}

// ---------------- diffusion gate ----------------
__global__ void gamma_kernel(const float* __restrict__ pooled, const float* __restrict__ Wg,
                             const float* __restrict__ bg, float* __restrict__ gamma) {
  const int lane = threadIdx.x & 63;
  const int w = threadIdx.x >> 6;
  const int o = blockIdx.x * 4 + w;
  const int b = o / 768;
  const int j = o - b * 768;
  const float* pr = pooled + b * 768;
  const float* wr = Wg + (size_t)j * 768;
  float s = 0.0f;
  #pragma unroll
  for (int c = lane; c < 768; c += 64) s += pr[c] * wr[c];
  #pragma unroll
  for (int off = 32; off > 0; off >>= 1) s += __shfl_down(s, off);
  if (lane == 0) {
    float gin = s + bg[j];
    gamma[o] = fminf(softplusf(gin), 0.05f);
  }
}

// ---------------- W_out -> bf16 ----------------
__global__ void cvt_bf16_kernel(const float* __restrict__ src, unsigned short* __restrict__ dst, int n) {
  int i = blockIdx.x * 256 + threadIdx.x;
  if (i < n) dst[i] = f2bf(src[i]);
}

// ---------------- symplectic reaction-diffusion PDE (wave-per-channel) ------
// R17-verified math/load. Output: LDS bounce fld[4][4096] (u then v) ->
// Ablk[b][g][n][4ch]; u -> group cg, v -> group 192+cg (cg = c0/4).
// Gather (FIXED): thread t, chunk grp: nn = grp*1024 + t*4 —
// LDS reads lane-consecutive (4 lanes/bank = minimum), stores 2KB-contiguous.
__global__ __launch_bounds__(256, 1) void pde_kernel(
    const float* __restrict__ xT, const float* __restrict__ gamma,
    const float* __restrict__ alpha, const float* __restrict__ beta,
    const int* __restrict__ kp, unsigned short* __restrict__ Ablk) {
  __shared__ __align__(16) unsigned short fld[4][4096];   // 32KB, reused u->v
  const int w = threadIdx.x >> 6;          // wave 0..3 -> channel c0+w
  const int lane = threadIdx.x & 63;
  const int t = threadIdx.x;
  const int b = blockIdx.x / 192;          // 1536 blocks = 8 b x 192 cgroups
  const int cg = blockIdx.x - b * 192;
  const int c = cg * 4 + w;
  const int lx = lane & 7;
  const int ly = lane >> 3;

  int ks = *kp; if (ks < 1) ks = 1;
  const float dt = 1.0f / (float)ks;
  const float hdt = 0.5f * dt;
  const float ae = 0.2f * tanhf(alpha[c]);
  const float be = fmaxf(softplusf(beta[c]), 1e-4f);
  const float g = gamma[b * 768 + c];
  const float c1n = -0.5f * dt * g;   // v -= c1*lap  ->  v += c1n*lap
  const float c2p = dt * g;

  const int laneL = (ly << 3) | ((lx + 7) & 7);
  const int laneR = (ly << 3) | ((lx + 1) & 7);
  const int laneU = (((ly + 7) & 7) << 3) | lx;   // holds rows above (row-1)
  const int laneD = (((ly + 1) & 7) << 3) | lx;   // holds rows below (row+1)

  float u[64], v[64];
  const float* xp = xT + ((size_t)b * 768 + c) * 4096;
  #pragma unroll
  for (int r = 0; r < 8; ++r) {
    const float4* src = (const float4*)(xp + (ly * 8 + r) * 64 + lx * 8);
    const float4 a0 = src[0], a1 = src[1];
    u[r * 8 + 0] = a0.x; u[r * 8 + 1] = a0.y; u[r * 8 + 2] = a0.z; u[r * 8 + 3] = a0.w;
    u[r * 8 + 4] = a1.x; u[r * 8 + 5] = a1.y; u[r * 8 + 6] = a1.z; u[r * 8 + 7] = a1.w;
  }
  #pragma unroll
  for (int i = 0; i < 64; ++i) v[i] = 0.0f;

  // G += COEF * lap(F): halo via 32 shfls, interior in-register.
  #define LAP_PHASE(F, G, COEF)                                               \
    {                                                                         \
      float lh[8], rh[8], uh[8], dh[8];                                       \
      _Pragma("unroll")                                                       \
      for (int r = 0; r < 8; ++r) {                                           \
        lh[r] = __shfl(F[r * 8 + 7], laneL);                                  \
        rh[r] = __shfl(F[r * 8 + 0], laneR);                                  \
        uh[r] = __shfl(F[56 + r], laneU);                                     \
        dh[r] = __shfl(F[r], laneD);                                          \
      }                                                                       \
      _Pragma("unroll")                                                       \
      for (int r = 0; r < 8; ++r) {                                           \
        _Pragma("unroll")                                                     \
        for (int j = 0; j < 8; ++j) {                                         \
          const float lf = (j == 0) ? lh[r] : F[r * 8 + j - 1];               \
          const float rt = (j == 7) ? rh[r] : F[r * 8 + j + 1];               \
          const float up = (r == 0) ? uh[j] : F[(r - 1) * 8 + j];             \
          const float dn = (r == 7) ? dh[j] : F[(r + 1) * 8 + j];             \
          const float lap = (lf + rt) + (up + dn) - 4.0f * F[r * 8 + j];      \
          G[r * 8 + j] = fmaf((COEF), lap, G[r * 8 + j]);                     \
        }                                                                     \
      }                                                                       \
    }

  for (int s = 0; s < ks; ++s) {
    #pragma unroll
    for (int i = 0; i < 64; ++i) {
      const float q = u[i] * u[i] + v[i] * v[i];
      const float rate = fminf(fmaxf(ae - be * q, -1.0f), 1.0f);
      const float tt = hdt * rate;
      u[i] = fmaf(tt, u[i], u[i]);
      v[i] = fmaf(tt, v[i], v[i]);
    }
    LAP_PHASE(u, v, c1n)
    LAP_PHASE(v, u, c2p)
    LAP_PHASE(u, v, c1n)
    #pragma unroll
    for (int i = 0; i < 64; ++i) {
      const float q = u[i] * u[i] + v[i] * v[i];
      const float rate = fminf(fmaxf(ae - be * q, -1.0f), 1.0f);
      const float tt = hdt * rate;
      u[i] = fmaf(tt, u[i], u[i]);
      v[i] = fmaf(tt, v[i], v[i]);
    }
  }
  #undef LAP_PHASE

  // ---- output: wave w -> fld[w]; barrier; conflict-free coalesced gather.
  #define DUMP(F, gbase)                                                      \
    {                                                                         \
      _Pragma("unroll")                                                       \
      for (int r = 0; r < 8; ++r) {                                           \
        short8v o;                                                            \
        _Pragma("unroll")                                                     \
        for (int j = 0; j < 8; ++j) o[j] = (short)f2bf(F[r * 8 + j]);         \
        *(short8v*)(&fld[w][(ly * 8 + r) * 64 + lx * 8]) = o;                 \
      }                                                                       \
      __syncthreads();                                                        \
      {                                                                       \
        unsigned short* ab = Ablk + (size_t)(b * 384 + (gbase) + cg) * 16384; \
        _Pragma("unroll")                                                     \
        for (int grp = 0; grp < 4; ++grp) {                                   \
          const int nn = grp * 1024 + t * 4;                                  \
          short4v s0 = *(const short4v*)(&fld[0][nn]);                        \
          short4v s1 = *(const short4v*)(&fld[1][nn]);                        \
          short4v s2 = *(const short4v*)(&fld[2][nn]);                        \
          short4v s3 = *(const short4v*)(&fld[3][nn]);                        \
          short8v o1, o2;                                                     \
          o1[0] = s0[0]; o1[1] = s1[0]; o1[2] = s2[0]; o1[3] = s3[0];         \
          o1[4] = s0[1]; o1[5] = s1[1]; o1[6] = s2[1]; o1[7] = s3[1];         \
          o2[0] = s0[2]; o2[1] = s1[2]; o2[2] = s2[2]; o2[3] = s3[2];         \
          o2[4] = s0[3]; o2[5] = s1[3]; o2[6] = s2[3]; o2[7] = s3[3];         \
          *(short8v*)(ab + (size_t)nn * 4) = o1;                              \
          *(short8v*)(ab + (size_t)nn * 4 + 8) = o2;                          \
        }                                                                     \
      }                                                                       \
      __syncthreads();                                                        \
    }

  DUMP(u, 0)
  DUMP(v, 192)
  #undef DUMP
}

// ---------------- bf16 MFMA GEMM (R18-verified A-from-Ablk, ~140us) ---------
// out = A @ W^T + x*D.  128x128 tile, BK=64 (=16 groups of 4ch), 2-buf LDS,
// vmcnt(8), XCD remap.  A LDS tile [16g][128n][4ch] (512 hw per g), staged
// 1KB-contiguous; frag = 2x ds_read_b64 at g*512+row*4 (conflict-free).
// B path/swizzle/epilogue R7-exact.
__global__ __launch_bounds__(256) void gemm_kernel(
    const unsigned short* __restrict__ Ablk, // [8][384][4096][4] bf16
    const unsigned short* __restrict__ Bt,   // [768][1536] bf16 (W_out)
    const float* __restrict__ x,             // [32768][768]
    const float* __restrict__ Dv,            // [768]
    float* __restrict__ out) {               // [32768][768]
  __shared__ __align__(16) unsigned short Als[2][128 * 64];
  __shared__ __align__(16) unsigned short Bls[2][128 * 64];
  const int tid = threadIdx.x;
  const int lane = tid & 63;
  const int w = tid >> 6;       // wave 0..3
  const int wr = w >> 1;        // wave row (2x2 waves, each 64x64 of C)
  const int wc = w & 1;

  // XCD-chunked remap: id -> (m-block, n-block). 1536 blocks, 8 XCDs.
  const int id = blockIdx.x;
  const int xcd = id & 7;
  const int seq = id >> 3;          // 0..191
  const int nb = seq % 6;
  const int mb = (seq / 6) * 8 + xcd;
  const int m0 = mb * 128;
  const int n0 = nb * 128;
  const int bb = m0 >> 12;          // batch of this m-panel
  const int nb0 = m0 & 4095;        // n offset within batch

  // B staging swizzle (R7): load global logical slot (lane&7)^(lane>>3)
  const int src_col = (((lane & 7) ^ (lane >> 3)) * 8);   // halfwords
  // read-side (B): quarter-wave q, row-low bits rlow
  const int q = lane >> 4;
  const int rlow = lane & 7;

  float4v acc[4][4];
  #pragma unroll
  for (int a = 0; a < 4; ++a)
    #pragma unroll
    for (int bq = 0; bq < 4; ++bq)
      acc[a][bq] = (float4v){0.f, 0.f, 0.f, 0.f};

  // per-wave: 4 A + 4 B global_load_lds, 16B each (vmcnt budget 8, as R7)
  #define STAGE(bufi, kt)                                                     \
    _Pragma("unroll")                                                         \
    for (int i = 0; i < 4; ++i) {                                             \
      const int g_off = w * 4 + i;          /* 0..15 */                       \
      __builtin_amdgcn_global_load_lds(                                       \
          (const __attribute__((address_space(1))) void*)(Ablk + ((size_t)(bb * 384 + (kt) * 16 + g_off) * 4096 + nb0) * 4 + lane * 8), \
          (__attribute__((address_space(3))) void*)(&Als[bufi][g_off * 512]), 16, 0, 0); \
      const int rowblk = g_off * 8;                                           \
      const int row = rowblk + (lane >> 3);                                   \
      __builtin_amdgcn_global_load_lds(                                       \
          (const __attribute__((address_space(1))) void*)(Bt + (size_t)(n0 + row) * 1536 + (kt) * 64 + src_col), \
          (__attribute__((address_space(3))) void*)(&Bls[bufi][rowblk * 64]), 16, 0, 0); \
    }

  STAGE(0, 0)
  int cur = 0;
  for (int kt = 0; kt < 24; ++kt) {
    // bar1: all waves' reads of buf[cur^1] retired -> safe to re-stage
    __builtin_amdgcn_s_barrier();
    if (kt < 23) {
      STAGE(cur ^ 1, kt + 1)
      asm volatile("s_waitcnt vmcnt(8)" ::: "memory");   // wait prev 8, keep new 8 in flight
    } else {
      asm volatile("s_waitcnt vmcnt(0)" ::: "memory");   // last tile: drain
    }
    // bar2: every wave has its current buffer's loads complete
    __builtin_amdgcn_s_barrier();
    __builtin_amdgcn_sched_barrier(0);
    #pragma unroll
    for (int ksub = 0; ksub < 2; ++ksub) {
      const int soff = ((ksub * 4 + q) ^ rlow) * 8;    // B swizzled slot
      const int g0 = (ksub * 4 + q) * 2;               // A group pair
      short8v af[4], bf[4];
      #pragma unroll
      for (int mi = 0; mi < 4; ++mi) {
        const int row = wr * 64 + mi * 16 + (lane & 15);
        short4v lo = *(const short4v*)(&Als[cur][g0 * 512 + row * 4]);
        short4v hi = *(const short4v*)(&Als[cur][(g0 + 1) * 512 + row * 4]);
        af[mi][0] = lo[0]; af[mi][1] = lo[1]; af[mi][2] = lo[2]; af[mi][3] = lo[3];
        af[mi][4] = hi[0]; af[mi][5] = hi[1]; af[mi][6] = hi[2]; af[mi][7] = hi[3];
      }
      #pragma unroll
      for (int ni = 0; ni < 4; ++ni)
        bf[ni] = *(const short8v*)(&Bls[cur][(wc * 64 + ni * 16 + (lane & 15)) * 64 + soff]);
      #pragma unroll
      for (int mi = 0; mi < 4; ++mi)
        #pragma unroll
        for (int ni = 0; ni < 4; ++ni)
          acc[mi][ni] = __builtin_amdgcn_mfma_f32_16x16x32_bf16(af[mi], bf[ni], acc[mi][ni], 0, 0, 0);
    }
    cur ^= 1;
  }
  #undef STAGE

  // epilogue: out = acc + x*D  (C/D layout: col=lane&15, row=(lane>>4)*4+r)
  #pragma unroll
  for (int ni = 0; ni < 4; ++ni) {
    const int col = n0 + wc * 64 + ni * 16 + (lane & 15);
    const float dcol = Dv[col];
    #pragma unroll
    for (int mi = 0; mi < 4; ++mi) {
      #pragma unroll
      for (int r = 0; r < 4; ++r) {
        const int row = m0 + wr * 64 + mi * 16 + (lane >> 4) * 4 + r;
        const size_t idx = (size_t)row * 768 + col;
        out[idx] = acc[mi][ni][r] + x[idx] * dcol;
      }
    }
  }
}

// ---------------------------------------------------------------------------
extern "C" void kernel_launch(void* const* d_in, const int* in_sizes, int n_in,
                              void* d_out, int out_size, void* d_ws, size_t ws_size,
                              hipStream_t stream) {
  const float* x     = (const float*)d_in[0];
  const float* Wg    = (const float*)d_in[1];
  const float* bg    = (const float*)d_in[2];
  const float* alpha = (const float*)d_in[3];
  const float* beta  = (const float*)d_in[4];
  const float* Wout  = (const float*)d_in[5];
  const float* Dv    = (const float*)d_in[6];
  const int*   kp    = (const int*)d_in[7];
  float* out = (float*)d_out;

  // workspace layout (~195 MiB, R18-verified)
  //   partial aliases A_blk (partial dead after pool_reduce, before pde)
  //   xT is SEPARATE from A_blk (pde reads xT while writing A_blk)
  char* ws = (char*)d_ws;
  unsigned short* Ablk = (unsigned short*)(ws);                // 8*384*4096*4*2 = 100663296
  float* partial       = (float*)(ws);                         // 64*8*768*4 (alias Ablk)
  float* xT            = (float*)(ws + 100663296);             // 8*768*4096*4   = 100663296
  unsigned short* Wb   = (unsigned short*)(ws + 201326592);    // 768*1536*2     = 2359296
  float* pooled        = (float*)(ws + 203685888);             // 6144*4
  float* gam           = (float*)(ws + 203710464);             // 6144*4

  transpose_x_kernel<<<dim3(12, 64, 8), 256, 0, stream>>>(x, xT, partial);
  pool_reduce_kernel<<<24, 256, 0, stream>>>(partial, pooled);
  gamma_kernel<<<1536, 256, 0, stream>>>(pooled, Wg, bg, gam);
  cvt_bf16_kernel<<<(768 * 1536 + 255) / 256, 256, 0, stream>>>(Wout, Wb, 768 * 1536);
  pde_kernel<<<1536, 256, 0, stream>>>(xT, gam, alpha, beta, kp, Ablk);
  gemm_kernel<<<1536, 256, 0, stream>>>(Ablk, Wb, x, Dv, out);
}